// Round 2
// baseline (174.573 us; speedup 1.0000x reference)
//
#include <hip/hip_runtime.h>

// YOLO-style loss, B=131072, GRID=7, CELLS=49, 11 floats/cell.
// outputs: (B,539) fp32 -> linear stream of 11-float cells (cell g at float 11g).
// target:  (B,2,4) fp32.
// Memory-bound: ~287 MB read -> ~46us floor @ 6.3 TB/s.
// R1: CPC 1024->512 (LDS 44->22.5KB, 3->7 blocks/CU, 12->28 waves/CU) +
//     global_load_lds width=16 staging (no VGPR round-trip).

constexpr int BLOCK = 256;
constexpr int CPC = 512;                        // cells per chunk (per block)
constexpr int FLOATS_PER_CHUNK = CPC * 11;      // 5632
constexpr int F4_PER_CHUNK = FLOATS_PER_CHUNK / 4;  // 1408
constexpr int TOTAL_CELLS = 131072 * 49;        // 6422528
constexpr int NCHUNKS = TOTAL_CELLS / CPC;      // 12544 (exact)

__global__ __launch_bounds__(BLOCK) void yolo_loss_kernel(
    const float* __restrict__ outputs,
    const float* __restrict__ target,
    double* __restrict__ acc)
{
#pragma clang fp contract(off)
    __shared__ float4 ldsv[F4_PER_CHUNK];       // 22528 B
    __shared__ double wred[BLOCK / 64];

    const int t = threadIdx.x;
    const unsigned chunk = blockIdx.x;

    // ---- stage 512 cells (1408 float4) direct global->LDS.
    // LDS dest = wave-uniform base + lane*16 (linear layout) -> valid for
    // global_load_lds. 5 full rounds + one half round (t<128 is wave-aligned).
    const float4* src = reinterpret_cast<const float4*>(outputs)
                        + (size_t)chunk * F4_PER_CHUNK;
#pragma unroll
    for (int i = 0; i < 5; ++i) {
        __builtin_amdgcn_global_load_lds(
            (const __attribute__((address_space(1))) void*)(src + t + BLOCK * i),
            (__attribute__((address_space(3))) void*)(ldsv + t + BLOCK * i),
            16, 0, 0);
    }
    if (t < 128) {
        __builtin_amdgcn_global_load_lds(
            (const __attribute__((address_space(1))) void*)(src + t + 1280),
            (__attribute__((address_space(3))) void*)(ldsv + t + 1280),
            16, 0, 0);
    }
    __syncthreads();

    const float* lds = reinterpret_cast<const float*>(ldsv);
    const float4* tg4 = reinterpret_cast<const float4*>(target);
    const float CW = 1.0f / 7.0f;

    double a = 0.0;
#pragma unroll
    for (int q = 0; q < 2; ++q) {
        const int cl = t + BLOCK * q;               // cell within chunk
        const unsigned g = chunk * CPC + cl;        // global cell index
        const unsigned b = g / 49u;                 // sample
        const unsigned s = g - b * 49u;             // cell within sample
        const float xl = (float)(s % 7u) / 7.0f;    // exact fp32 div, matches numpy
        const float yl = (float)(s / 7u) / 7.0f;

        const float4 T0 = tg4[2u * b];
        const float4 T1 = tg4[2u * b + 1u];
        const bool v1 = (T1.x != -1.0f);

        const float* cp = lds + cl * 11;            // 11t base: coprime w/ 32 banks

        float conf0, conf1, term0, term1;
        bool one0, one1;
        {   // box j=0 (always valid)
            const float px = cp[0], py = cp[1], pw = cp[2], ph = cp[3], pc = cp[4];
            const float tx = T0.x, ty = T0.y, tw = T0.z, th = T0.w;
            const float ix = fabsf(fmaxf(px - 0.5f * pw, tx - 0.5f * tw)
                                 - fminf(px + 0.5f * pw, tx + 0.5f * tw));
            const float iy = fabsf(fmaxf(py - 0.5f * ph, ty - 0.5f * th)
                                 - fminf(py + 0.5f * ph, ty + 0.5f * th));
            const float inter = ix * iy;
            const float uni = pw * ph + tw * th - inter;
            conf0 = inter / uni;
            one0 = (xl <= tx) && (tx <= xl + CW) && (yl <= ty) && (ty <= yl + CW);
            const float d0 = tx - px, d1 = ty - py;
            const float d2 = sqrtf(tw) - sqrtf(pw);
            const float d3 = sqrtf(th) - sqrtf(ph);
            const float coord = ((d0 * d0 + d1 * d1) + d2 * d2) + d3 * d3;
            const float dc = conf0 - pc;
            term0 = one0 ? (5.0f * coord + dc * dc) : (0.5f * pc * pc);
        }
        {   // box j=1 (valid iff T1.x != -1)
            const float px = cp[5], py = cp[6], pw = cp[7], ph = cp[8], pc = cp[9];
            const float tx = T1.x, ty = T1.y, tw = T1.z, th = T1.w;
            const float ix = fabsf(fmaxf(px - 0.5f * pw, tx - 0.5f * tw)
                                 - fminf(px + 0.5f * pw, tx + 0.5f * tw));
            const float iy = fabsf(fmaxf(py - 0.5f * ph, ty - 0.5f * th)
                                 - fminf(py + 0.5f * ph, ty + 0.5f * th));
            const float inter = ix * iy;
            const float uni = pw * ph + tw * th - inter;
            conf1 = inter / uni;
            const bool inx = (xl <= tx) && (tx <= xl + CW);
            const bool iny = (yl <= ty) && (ty <= yl + CW);
            one1 = inx && iny && v1;
            const float d0 = tx - px, d1 = ty - py;
            const float d2 = sqrtf(tw) - sqrtf(pw);
            const float d3 = sqrtf(th) - sqrtf(ph);
            const float coord = ((d0 * d0 + d1 * d1) + d2 * d2) + d3 * d3;
            const float dc = conf1 - pc;
            term1 = one1 ? (5.0f * coord + dc * dc)
                         : (v1 ? (0.5f * pc * pc) : 0.0f);
        }
        // class term
        const float sum_conf = conf0 + (v1 ? conf1 : 0.0f);
        float cls = 0.0f;
        if (one0 || one1) {
            const float d = cp[10] - sum_conf;
            cls = d * d;
        }
        a += (double)term0 + (double)term1 + (double)cls;
    }

    // ---- reduction: wave shfl -> LDS -> block -> global fp64 atomic
#pragma unroll
    for (int off = 32; off > 0; off >>= 1)
        a += __shfl_down(a, off);
    if ((t & 63) == 0) wred[t >> 6] = a;
    __syncthreads();
    if (t == 0) {
        double s = wred[0] + wred[1] + wred[2] + wred[3];
        atomicAdd(acc, s);
    }
}

__global__ void finalize_kernel(const double* __restrict__ acc,
                                float* __restrict__ out)
{
    out[0] = (float)acc[0];
}

extern "C" void kernel_launch(void* const* d_in, const int* in_sizes, int n_in,
                              void* d_out, int out_size, void* d_ws, size_t ws_size,
                              hipStream_t stream)
{
    const float* outputs = (const float*)d_in[0];
    const float* target  = (const float*)d_in[1];
    float* out = (float*)d_out;
    double* acc = (double*)d_ws;

    hipMemsetAsync(acc, 0, sizeof(double), stream);
    yolo_loss_kernel<<<NCHUNKS, BLOCK, 0, stream>>>(outputs, target, acc);
    finalize_kernel<<<1, 1, 0, stream>>>(acc, out);
}

// Round 3
// 77.005 us; speedup vs baseline: 2.2670x; 2.2670x over previous
//
#include <hip/hip_runtime.h>

// YOLO-style loss, B=131072, GRID=7, CELLS=49, 11 floats/cell.
// outputs: (B,539) fp32 -> linear stream of 11-float cells (cell g at float 11g).
// target:  (B,2,4) fp32.
// R2: kill the single-address fp64 atomicAdd (measured ~15ns/block serial ->
//     it WAS the critical path in R0/R1). Blocks write partials to d_ws;
//     a second kernel reduces them. Staging reverted to R0 (proven) layout.

constexpr int BLOCK = 256;
constexpr int CPC = 1024;                       // cells per chunk (per block)
constexpr int FLOATS_PER_CHUNK = CPC * 11;      // 11264
constexpr int F4_PER_CHUNK = FLOATS_PER_CHUNK / 4;  // 2816
constexpr int F4_PER_THREAD = F4_PER_CHUNK / BLOCK; // 11
constexpr int TOTAL_CELLS = 131072 * 49;        // 6422528
constexpr int NCHUNKS = TOTAL_CELLS / CPC;      // 6272 (exact)

__global__ __launch_bounds__(BLOCK) void yolo_loss_kernel(
    const float* __restrict__ outputs,
    const float* __restrict__ target,
    double* __restrict__ part)
{
#pragma clang fp contract(off)
    __shared__ float lds[FLOATS_PER_CHUNK];
    __shared__ double wred[BLOCK / 64];

    const int t = threadIdx.x;
    const unsigned chunk = blockIdx.x;

    // ---- stage 1024 cells (11264 floats) into LDS, 11 coalesced float4/thread
    const float4* src = reinterpret_cast<const float4*>(outputs)
                        + (size_t)chunk * F4_PER_CHUNK;
    float4* l4 = reinterpret_cast<float4*>(lds);
#pragma unroll
    for (int i = 0; i < F4_PER_THREAD; ++i)
        l4[t + BLOCK * i] = src[t + BLOCK * i];
    __syncthreads();

    const float4* tg4 = reinterpret_cast<const float4*>(target);
    const float CW = 1.0f / 7.0f;

    double a = 0.0;
#pragma unroll
    for (int q = 0; q < 4; ++q) {
        const int cl = t + BLOCK * q;               // cell within chunk
        const unsigned g = chunk * CPC + cl;        // global cell index
        const unsigned b = g / 49u;                 // sample
        const unsigned s = g - b * 49u;             // cell within sample
        const float xl = (float)(s % 7u) / 7.0f;    // exact fp32 div, matches numpy
        const float yl = (float)(s / 7u) / 7.0f;

        const float4 T0 = tg4[2u * b];
        const float4 T1 = tg4[2u * b + 1u];
        const bool v1 = (T1.x != -1.0f);

        const float* cp = lds + cl * 11;            // 11t base: coprime w/ 32 banks

        float conf0, conf1, term0, term1;
        bool one0, one1;
        {   // box j=0 (always valid)
            const float px = cp[0], py = cp[1], pw = cp[2], ph = cp[3], pc = cp[4];
            const float tx = T0.x, ty = T0.y, tw = T0.z, th = T0.w;
            const float ix = fabsf(fmaxf(px - 0.5f * pw, tx - 0.5f * tw)
                                 - fminf(px + 0.5f * pw, tx + 0.5f * tw));
            const float iy = fabsf(fmaxf(py - 0.5f * ph, ty - 0.5f * th)
                                 - fminf(py + 0.5f * ph, ty + 0.5f * th));
            const float inter = ix * iy;
            const float uni = pw * ph + tw * th - inter;
            conf0 = inter / uni;
            one0 = (xl <= tx) && (tx <= xl + CW) && (yl <= ty) && (ty <= yl + CW);
            const float d0 = tx - px, d1 = ty - py;
            const float d2 = sqrtf(tw) - sqrtf(pw);
            const float d3 = sqrtf(th) - sqrtf(ph);
            const float coord = ((d0 * d0 + d1 * d1) + d2 * d2) + d3 * d3;
            const float dc = conf0 - pc;
            term0 = one0 ? (5.0f * coord + dc * dc) : (0.5f * pc * pc);
        }
        {   // box j=1 (valid iff T1.x != -1)
            const float px = cp[5], py = cp[6], pw = cp[7], ph = cp[8], pc = cp[9];
            const float tx = T1.x, ty = T1.y, tw = T1.z, th = T1.w;
            const float ix = fabsf(fmaxf(px - 0.5f * pw, tx - 0.5f * tw)
                                 - fminf(px + 0.5f * pw, tx + 0.5f * tw));
            const float iy = fabsf(fmaxf(py - 0.5f * ph, ty - 0.5f * th)
                                 - fminf(py + 0.5f * ph, ty + 0.5f * th));
            const float inter = ix * iy;
            const float uni = pw * ph + tw * th - inter;
            conf1 = inter / uni;
            const bool inx = (xl <= tx) && (tx <= xl + CW);
            const bool iny = (yl <= ty) && (ty <= yl + CW);
            one1 = inx && iny && v1;
            const float d0 = tx - px, d1 = ty - py;
            const float d2 = sqrtf(tw) - sqrtf(pw);
            const float d3 = sqrtf(th) - sqrtf(ph);
            const float coord = ((d0 * d0 + d1 * d1) + d2 * d2) + d3 * d3;
            const float dc = conf1 - pc;
            term1 = one1 ? (5.0f * coord + dc * dc)
                         : (v1 ? (0.5f * pc * pc) : 0.0f);
        }
        // class term
        const float sum_conf = conf0 + (v1 ? conf1 : 0.0f);
        float cls = 0.0f;
        if (one0 || one1) {
            const float d = cp[10] - sum_conf;
            cls = d * d;
        }
        a += (double)term0 + (double)term1 + (double)cls;
    }

    // ---- reduction: wave shfl -> LDS -> block partial -> d_ws (NO atomics)
#pragma unroll
    for (int off = 32; off > 0; off >>= 1)
        a += __shfl_down(a, off);
    if ((t & 63) == 0) wred[t >> 6] = a;
    __syncthreads();
    if (t == 0)
        part[chunk] = wred[0] + wred[1] + wred[2] + wred[3];
}

__global__ __launch_bounds__(BLOCK) void reduce_kernel(
    const double* __restrict__ part, float* __restrict__ out)
{
    __shared__ double wred[BLOCK / 64];
    const int t = threadIdx.x;
    double a = 0.0;
    for (int i = t; i < NCHUNKS; i += BLOCK)
        a += part[i];
#pragma unroll
    for (int off = 32; off > 0; off >>= 1)
        a += __shfl_down(a, off);
    if ((t & 63) == 0) wred[t >> 6] = a;
    __syncthreads();
    if (t == 0)
        out[0] = (float)(wred[0] + wred[1] + wred[2] + wred[3]);
}

extern "C" void kernel_launch(void* const* d_in, const int* in_sizes, int n_in,
                              void* d_out, int out_size, void* d_ws, size_t ws_size,
                              hipStream_t stream)
{
    const float* outputs = (const float*)d_in[0];
    const float* target  = (const float*)d_in[1];
    float* out = (float*)d_out;
    double* part = (double*)d_ws;   // NCHUNKS doubles = 50,176 B

    yolo_loss_kernel<<<NCHUNKS, BLOCK, 0, stream>>>(outputs, target, part);
    reduce_kernel<<<1, BLOCK, 0, stream>>>(part, out);
}

// Round 4
// 58.169 us; speedup vs baseline: 3.0011x; 1.3238x over previous
//
#include <hip/hip_runtime.h>

// YOLO-style loss, B=131072, GRID=7, CELLS=49, 11 floats/cell.
// outputs: (B,539) fp32 -> linear stream of 11-float cells (cell g at float 11g).
// target:  (B,2,4) fp32.
// R2: non-atomic partial-store reduction (atomic was ~15ns/block serial). 77us.
// R3: CPC 1024->512: LDS 44->22.5KB, 3->7 blocks/CU, 12->28 waves/CU.
//     Single-variable change vs R2 (staging + reduction structure unchanged).

constexpr int BLOCK = 256;
constexpr int CPC = 512;                        // cells per chunk (per block)
constexpr int FLOATS_PER_CHUNK = CPC * 11;      // 5632
constexpr int F4_PER_CHUNK = FLOATS_PER_CHUNK / 4;  // 1408 = 5.5 * 256
constexpr int TOTAL_CELLS = 131072 * 49;        // 6422528
constexpr int NCHUNKS = TOTAL_CELLS / CPC;      // 12544 (exact)

__global__ __launch_bounds__(BLOCK) void yolo_loss_kernel(
    const float* __restrict__ outputs,
    const float* __restrict__ target,
    double* __restrict__ part)
{
#pragma clang fp contract(off)
    __shared__ float lds[FLOATS_PER_CHUNK];     // 22528 B
    __shared__ double wred[BLOCK / 64];

    const int t = threadIdx.x;
    const unsigned chunk = blockIdx.x;

    // ---- stage 512 cells (1408 float4) into LDS: 5 full rounds + half round
    const float4* src = reinterpret_cast<const float4*>(outputs)
                        + (size_t)chunk * F4_PER_CHUNK;
    float4* l4 = reinterpret_cast<float4*>(lds);
#pragma unroll
    for (int i = 0; i < 5; ++i)
        l4[t + BLOCK * i] = src[t + BLOCK * i];
    if (t < 128)                                 // wave-aligned half round
        l4[t + 1280] = src[t + 1280];
    __syncthreads();

    const float4* tg4 = reinterpret_cast<const float4*>(target);
    const float CW = 1.0f / 7.0f;

    double a = 0.0;
#pragma unroll
    for (int q = 0; q < 2; ++q) {
        const int cl = t + BLOCK * q;               // cell within chunk
        const unsigned g = chunk * CPC + cl;        // global cell index
        const unsigned b = g / 49u;                 // sample
        const unsigned s = g - b * 49u;             // cell within sample
        const float xl = (float)(s % 7u) / 7.0f;    // exact fp32 div, matches numpy
        const float yl = (float)(s / 7u) / 7.0f;

        const float4 T0 = tg4[2u * b];
        const float4 T1 = tg4[2u * b + 1u];
        const bool v1 = (T1.x != -1.0f);

        const float* cp = lds + cl * 11;            // 11t base: coprime w/ 32 banks

        float conf0, conf1, term0, term1;
        bool one0, one1;
        {   // box j=0 (always valid)
            const float px = cp[0], py = cp[1], pw = cp[2], ph = cp[3], pc = cp[4];
            const float tx = T0.x, ty = T0.y, tw = T0.z, th = T0.w;
            const float ix = fabsf(fmaxf(px - 0.5f * pw, tx - 0.5f * tw)
                                 - fminf(px + 0.5f * pw, tx + 0.5f * tw));
            const float iy = fabsf(fmaxf(py - 0.5f * ph, ty - 0.5f * th)
                                 - fminf(py + 0.5f * ph, ty + 0.5f * th));
            const float inter = ix * iy;
            const float uni = pw * ph + tw * th - inter;
            conf0 = inter / uni;
            one0 = (xl <= tx) && (tx <= xl + CW) && (yl <= ty) && (ty <= yl + CW);
            const float d0 = tx - px, d1 = ty - py;
            const float d2 = sqrtf(tw) - sqrtf(pw);
            const float d3 = sqrtf(th) - sqrtf(ph);
            const float coord = ((d0 * d0 + d1 * d1) + d2 * d2) + d3 * d3;
            const float dc = conf0 - pc;
            term0 = one0 ? (5.0f * coord + dc * dc) : (0.5f * pc * pc);
        }
        {   // box j=1 (valid iff T1.x != -1)
            const float px = cp[5], py = cp[6], pw = cp[7], ph = cp[8], pc = cp[9];
            const float tx = T1.x, ty = T1.y, tw = T1.z, th = T1.w;
            const float ix = fabsf(fmaxf(px - 0.5f * pw, tx - 0.5f * tw)
                                 - fminf(px + 0.5f * pw, tx + 0.5f * tw));
            const float iy = fabsf(fmaxf(py - 0.5f * ph, ty - 0.5f * th)
                                 - fminf(py + 0.5f * ph, ty + 0.5f * th));
            const float inter = ix * iy;
            const float uni = pw * ph + tw * th - inter;
            conf1 = inter / uni;
            const bool inx = (xl <= tx) && (tx <= xl + CW);
            const bool iny = (yl <= ty) && (ty <= yl + CW);
            one1 = inx && iny && v1;
            const float d0 = tx - px, d1 = ty - py;
            const float d2 = sqrtf(tw) - sqrtf(pw);
            const float d3 = sqrtf(th) - sqrtf(ph);
            const float coord = ((d0 * d0 + d1 * d1) + d2 * d2) + d3 * d3;
            const float dc = conf1 - pc;
            term1 = one1 ? (5.0f * coord + dc * dc)
                         : (v1 ? (0.5f * pc * pc) : 0.0f);
        }
        // class term
        const float sum_conf = conf0 + (v1 ? conf1 : 0.0f);
        float cls = 0.0f;
        if (one0 || one1) {
            const float d = cp[10] - sum_conf;
            cls = d * d;
        }
        a += (double)term0 + (double)term1 + (double)cls;
    }

    // ---- reduction: wave shfl -> LDS -> block partial -> d_ws (NO atomics)
#pragma unroll
    for (int off = 32; off > 0; off >>= 1)
        a += __shfl_down(a, off);
    if ((t & 63) == 0) wred[t >> 6] = a;
    __syncthreads();
    if (t == 0)
        part[chunk] = wred[0] + wred[1] + wred[2] + wred[3];
}

constexpr int RBLOCK = 1024;
__global__ __launch_bounds__(RBLOCK) void reduce_kernel(
    const double* __restrict__ part, float* __restrict__ out)
{
    __shared__ double wred[RBLOCK / 64];
    const int t = threadIdx.x;
    double a = 0.0;
    for (int i = t; i < NCHUNKS; i += RBLOCK)
        a += part[i];
#pragma unroll
    for (int off = 32; off > 0; off >>= 1)
        a += __shfl_down(a, off);
    if ((t & 63) == 0) wred[t >> 6] = a;
    __syncthreads();
    if (t == 0) {
        double s = 0.0;
#pragma unroll
        for (int i = 0; i < RBLOCK / 64; ++i) s += wred[i];
        out[0] = (float)s;
    }
}

extern "C" void kernel_launch(void* const* d_in, const int* in_sizes, int n_in,
                              void* d_out, int out_size, void* d_ws, size_t ws_size,
                              hipStream_t stream)
{
    const float* outputs = (const float*)d_in[0];
    const float* target  = (const float*)d_in[1];
    float* out = (float*)d_out;
    double* part = (double*)d_ws;   // NCHUNKS doubles = 100,352 B

    yolo_loss_kernel<<<NCHUNKS, BLOCK, 0, stream>>>(outputs, target, part);
    reduce_kernel<<<1, RBLOCK, 0, stream>>>(part, out);
}